// Round 1
// baseline (422.201 us; speedup 1.0000x reference)
//
#include <hip/hip_runtime.h>
#include <math.h>

#define H 512
#define W 512
#define IMG (H*W)
#define NIMG 32           // 16 images from y_hat + 16 from y
#define BX 32
#define BY 8

__device__ __forceinline__ int reflect_idx(int i, int n) {
    // jnp.pad mode="reflect": -1 -> 1, -2 -> 2, n -> n-2, n+1 -> n-3
    if (i < 0) i = -i;
    if (i >= n) i = 2 * n - 2 - i;
    return i;
}

// ---------------------------------------------------------------------------
// Kernel 1: grayscale + 5x5 Gaussian blur (reflect border), both inputs fused.
// grid: (W/BX, H/BY, 32), block: (BX, BY)
// ---------------------------------------------------------------------------
__global__ __launch_bounds__(256) void k_blur(const float* __restrict__ yhat,
                                              const float* __restrict__ yy,
                                              float* __restrict__ blur) {
    __shared__ float sg[BY + 4][BX + 4 + 1];
    const int n = blockIdx.z;
    const float* src = (n < 16) ? (yhat + (size_t)n * 3 * IMG)
                                : (yy + (size_t)(n - 16) * 3 * IMG);
    const int x0 = blockIdx.x * BX - 2;
    const int y0 = blockIdx.y * BY - 2;
    const int tid = threadIdx.y * BX + threadIdx.x;

    for (int idx = tid; idx < (BY + 4) * (BX + 4); idx += BX * BY) {
        int sy = idx / (BX + 4);
        int sx = idx % (BX + 4);
        int iy = reflect_idx(y0 + sy, H);
        int ix = reflect_idx(x0 + sx, W);
        float r = src[(size_t)iy * W + ix];
        float g = src[(size_t)IMG + (size_t)iy * W + ix];
        float b = src[(size_t)2 * IMG + (size_t)iy * W + ix];
        sg[sy][sx] = 0.299f * r + 0.587f * g + 0.114f * b;
    }
    __syncthreads();

    const float w[5] = {0.05448868454964294f, 0.24420134200323332f,
                        0.4026199468942475f, 0.24420134200323332f,
                        0.05448868454964294f};
    const int ty = threadIdx.y, tx = threadIdx.x;
    float acc = 0.f;
#pragma unroll
    for (int u = 0; u < 5; u++) {
        float rowacc = 0.f;
#pragma unroll
        for (int v = 0; v < 5; v++) rowacc += w[v] * sg[ty + u][tx + v];
        acc += w[u] * rowacc;
    }
    blur[(size_t)n * IMG + (size_t)(y0 + 2 + ty) * W + (x0 + 2 + tx)] = acc;
}

// ---------------------------------------------------------------------------
// Kernel 2: Sobel (reflect border) + magnitude + direction bin + NMS
//           (zero-pad neighbors) + double threshold -> uint8 code {0,1,2}
// ---------------------------------------------------------------------------
__global__ __launch_bounds__(256) void k_nms(const float* __restrict__ blur,
                                             unsigned char* __restrict__ code) {
    __shared__ float sb[BY + 4][BX + 4 + 1];   // blur tile, halo 2 (reflect)
    __shared__ float sm[BY + 2][BX + 2 + 1];   // mag tile, halo 1 (zero outside)
    const int n = blockIdx.z;
    const float* src = blur + (size_t)n * IMG;
    const int x0 = blockIdx.x * BX - 2;
    const int y0 = blockIdx.y * BY - 2;
    const int tid = threadIdx.y * BX + threadIdx.x;

    for (int idx = tid; idx < (BY + 4) * (BX + 4); idx += BX * BY) {
        int sy = idx / (BX + 4);
        int sx = idx % (BX + 4);
        sb[sy][sx] = src[(size_t)reflect_idx(y0 + sy, H) * W + reflect_idx(x0 + sx, W)];
    }
    __syncthreads();

    for (int idx = tid; idx < (BY + 2) * (BX + 2); idx += BX * BY) {
        int my = idx / (BX + 2);
        int mx = idx % (BX + 2);
        int iy = y0 + 1 + my;
        int ix = x0 + 1 + mx;
        float m = 0.f;
        if (iy >= 0 && iy < H && ix >= 0 && ix < W) {
            float a00 = sb[my][mx],     a01 = sb[my][mx + 1],     a02 = sb[my][mx + 2];
            float a10 = sb[my + 1][mx],                           a12 = sb[my + 1][mx + 2];
            float a20 = sb[my + 2][mx], a21 = sb[my + 2][mx + 1], a22 = sb[my + 2][mx + 2];
            float gx = (a02 + 2.f * a12 + a22) - (a00 + 2.f * a10 + a20);
            float gy = (a20 + 2.f * a21 + a22) - (a00 + 2.f * a01 + a02);
            m = sqrtf(gx * gx + gy * gy + 1e-12f);
        }
        sm[my][mx] = m;
    }
    __syncthreads();

    const int ty = threadIdx.y, tx = threadIdx.x;
    float a00 = sb[ty + 1][tx + 1], a01 = sb[ty + 1][tx + 2], a02 = sb[ty + 1][tx + 3];
    float a10 = sb[ty + 2][tx + 1],                           a12 = sb[ty + 2][tx + 3];
    float a20 = sb[ty + 3][tx + 1], a21 = sb[ty + 3][tx + 2], a22 = sb[ty + 3][tx + 3];
    float gx = (a02 + 2.f * a12 + a22) - (a00 + 2.f * a10 + a20);
    float gy = (a20 + 2.f * a21 + a22) - (a00 + 2.f * a01 + a02);
    float mag = sm[ty + 1][tx + 1];

    float ang = atan2f(gy, gx);
    // b = mod(round(ang / (pi/4)), 4); rintf = round-half-even matches jnp.round
    int b = ((int)rintf(ang * 1.2732395447351628f)) & 3;
    const int pdy[4] = {0, 1, 1, 1};
    const int pdx[4] = {1, 1, 0, -1};
    float n1 = sm[ty + 1 + pdy[b]][tx + 1 + pdx[b]];
    float n2 = sm[ty + 1 - pdy[b]][tx + 1 - pdx[b]];
    float nms = (mag >= n1 && mag >= n2) ? mag : 0.f;
    unsigned char c = (nms >= 0.2f) ? (unsigned char)2
                                    : ((nms >= 0.1f) ? (unsigned char)1 : (unsigned char)0);
    code[(size_t)n * IMG + (size_t)(y0 + 2 + ty) * W + (x0 + 2 + tx)] = c;
}

// ---------------------------------------------------------------------------
// Kernel 3: one hysteresis iteration: weak (1) with strong (2) 8-neighbor -> 2
// ---------------------------------------------------------------------------
__global__ __launch_bounds__(256) void k_hyst(const unsigned char* __restrict__ in,
                                              unsigned char* __restrict__ outb) {
    const int n = blockIdx.z;
    const int x = blockIdx.x * BX + threadIdx.x;
    const int y = blockIdx.y * BY + threadIdx.y;
    const unsigned char* src = in + (size_t)n * IMG;
    size_t p = (size_t)y * W + x;
    unsigned char e = src[p];
    if (e == 1) {
        bool strong = false;
#pragma unroll
        for (int dy = -1; dy <= 1; dy++) {
#pragma unroll
            for (int dx = -1; dx <= 1; dx++) {
                int ny = y + dy, nx = x + dx;
                if (ny >= 0 && ny < H && nx >= 0 && nx < W)
                    strong = strong || (src[(size_t)ny * W + nx] == 2);
            }
        }
        if (strong) e = 2;
    }
    outb[(size_t)n * IMG + p] = e;
}

// ---------------------------------------------------------------------------
// Kernel 4: count pixels where strong(y_hat) != strong(y), scaled mean -> out
// ---------------------------------------------------------------------------
__global__ __launch_bounds__(256) void k_reduce(const unsigned char* __restrict__ codes,
                                                float* __restrict__ out) {
    __shared__ int ssum[256];
    const unsigned char* A = codes;
    const unsigned char* B = codes + (size_t)16 * IMG;
    const int total = 16 * IMG;
    int cnt = 0;
    for (int i = blockIdx.x * blockDim.x + threadIdx.x; i < total;
         i += gridDim.x * blockDim.x) {
        int a = (A[i] == 2);
        int b = (B[i] == 2);
        cnt += (a != b);
    }
    ssum[threadIdx.x] = cnt;
    __syncthreads();
    for (int s = 128; s > 0; s >>= 1) {
        if (threadIdx.x < s) ssum[threadIdx.x] += ssum[threadIdx.x + s];
        __syncthreads();
    }
    if (threadIdx.x == 0)
        atomicAdd(out, (float)ssum[0] * (1.0f / (float)(16 * IMG)));
}

extern "C" void kernel_launch(void* const* d_in, const int* in_sizes, int n_in,
                              void* d_out, int out_size, void* d_ws, size_t ws_size,
                              hipStream_t stream) {
    const float* yhat = (const float*)d_in[0];
    const float* yy = (const float*)d_in[1];

    const size_t blurBytes = (size_t)NIMG * IMG * sizeof(float);   // 33.5 MB
    float* blur = (float*)d_ws;
    unsigned char* bufA = (unsigned char*)d_ws + blurBytes;        // 8.4 MB
    unsigned char* bufB = bufA + (size_t)NIMG * IMG;               // 8.4 MB

    dim3 blk(BX, BY);
    dim3 grd(W / BX, H / BY, NIMG);

    k_blur<<<grd, blk, 0, stream>>>(yhat, yy, blur);
    k_nms<<<grd, blk, 0, stream>>>(blur, bufA);

    unsigned char* ping = bufA;
    unsigned char* pong = bufB;
    for (int i = 0; i < 10; i++) {
        k_hyst<<<grd, blk, 0, stream>>>(ping, pong);
        unsigned char* t = ping; ping = pong; pong = t;
    }

    hipMemsetAsync(d_out, 0, sizeof(float), stream);
    k_reduce<<<1024, 256, 0, stream>>>(ping, (float*)d_out);
}

// Round 2
// 213.198 us; speedup vs baseline: 1.9803x; 1.9803x over previous
//
#include <hip/hip_runtime.h>
#include <math.h>

#define H 512
#define W 512
#define IMG (H*W)
#define NIMG 32           // 16 images from y_hat + 16 from y

typedef unsigned long long u64;

__device__ __forceinline__ int reflect_idx(int i, int n) {
    // jnp.pad mode="reflect": -1 -> 1, -2 -> 2, n -> n-2, n+1 -> n-3
    if (i < 0) i = -i;
    if (i >= n) i = 2 * n - 2 - i;
    return i;
}

// ---------------------------------------------------------------------------
// Kernel 1: gray + separable 5x5 Gaussian (reflect) + Sobel (reflect) + mag +
// direction bin + NMS (zero-pad neighbors) + double threshold, emitted as
// strong/weak BITPLANES via __ballot. Tile 64x8, block (64,8)=512 thr.
// Plane layout: plane[img][row][word], 8 u64 words per 512-px row.
// ---------------------------------------------------------------------------
#define EBX 64
#define EBY 8

__global__ __launch_bounds__(512) void k_edges(const float* __restrict__ yhat,
                                               const float* __restrict__ yy,
                                               u64* __restrict__ strongP,
                                               u64* __restrict__ weakP) {
    __shared__ float sg[EBY + 8][EBX + 8 + 1];   // gray,  16 x 72 (+pad)
    __shared__ float ht[EBY + 8][EBX + 4 + 1];   // h-blur,16 x 68 (+pad)
    __shared__ float sb[EBY + 4][EBX + 4 + 1];   // blur,  12 x 68 (+pad)
    __shared__ float sm[EBY + 2][EBX + 2 + 1];   // mag,   10 x 66 (+pad)

    const int n = blockIdx.z;
    const float* src = (n < 16) ? (yhat + (size_t)n * 3 * IMG)
                                : (yy + (size_t)(n - 16) * 3 * IMG);
    const int x0 = blockIdx.x * EBX;
    const int y0 = blockIdx.y * EBY;
    const int tid = threadIdx.y * EBX + threadIdx.x;

    const float w0 = 0.05448868454964294f, w1 = 0.24420134200323332f,
                w2 = 0.4026199468942475f;
    const float wk[5] = {w0, w1, w2, w1, w0};

    // ---- gray tile, halo 4, reflect ----
    for (int idx = tid; idx < 16 * 72; idx += 512) {
        int sy = idx / 72, sx = idx % 72;
        int iy = reflect_idx(y0 - 4 + sy, H);
        int ix = reflect_idx(x0 - 4 + sx, W);
        float r = src[(size_t)iy * W + ix];
        float g = src[(size_t)IMG + (size_t)iy * W + ix];
        float b = src[(size_t)2 * IMG + (size_t)iy * W + ix];
        sg[sy][sx] = 0.299f * r + 0.587f * g + 0.114f * b;
    }
    __syncthreads();

    // ---- horizontal blur: 16 x 68, col center = x0-2+sx ----
    for (int idx = tid; idx < 16 * 68; idx += 512) {
        int sy = idx / 68, sx = idx % 68;
        float a = 0.f;
#pragma unroll
        for (int v = 0; v < 5; v++) a += wk[v] * sg[sy][sx + v];
        ht[sy][sx] = a;
    }
    __syncthreads();

    // ---- vertical blur: 12 x 68, row center = y0-2+sy ----
    for (int idx = tid; idx < 12 * 68; idx += 512) {
        int sy = idx / 68, sx = idx % 68;
        float a = 0.f;
#pragma unroll
        for (int u = 0; u < 5; u++) a += wk[u] * ht[sy + u][sx];
        sb[sy][sx] = a;
    }
    __syncthreads();

    // ---- magnitude: 10 x 66 at (y0-1+my, x0-1+mx); zero outside image ----
    for (int idx = tid; idx < 10 * 66; idx += 512) {
        int my = idx / 66, mx = idx % 66;
        int iy = y0 - 1 + my, ix = x0 - 1 + mx;
        float m = 0.f;
        if (iy >= 0 && iy < H && ix >= 0 && ix < W) {
            float a00 = sb[my][mx],     a01 = sb[my][mx + 1],     a02 = sb[my][mx + 2];
            float a10 = sb[my + 1][mx],                           a12 = sb[my + 1][mx + 2];
            float a20 = sb[my + 2][mx], a21 = sb[my + 2][mx + 1], a22 = sb[my + 2][mx + 2];
            float gx = (a02 + 2.f * a12 + a22) - (a00 + 2.f * a10 + a20);
            float gy = (a20 + 2.f * a21 + a22) - (a00 + 2.f * a01 + a02);
            m = sqrtf(gx * gx + gy * gy + 1e-12f);
        }
        sm[my][mx] = m;
    }
    __syncthreads();

    // ---- NMS + double threshold for own pixel ----
    const int ty = threadIdx.y, tx = threadIdx.x;
    float a00 = sb[ty + 1][tx + 1], a01 = sb[ty + 1][tx + 2], a02 = sb[ty + 1][tx + 3];
    float a10 = sb[ty + 2][tx + 1],                           a12 = sb[ty + 2][tx + 3];
    float a20 = sb[ty + 3][tx + 1], a21 = sb[ty + 3][tx + 2], a22 = sb[ty + 3][tx + 3];
    float gx = (a02 + 2.f * a12 + a22) - (a00 + 2.f * a10 + a20);
    float gy = (a20 + 2.f * a21 + a02 * 0.f + a22) - (a00 + 2.f * a01 + a02);
    float mag = sm[ty + 1][tx + 1];

    // bin = mod(round(atan2(gy,gx)/(pi/4)),4) via slope comparison
    float ax = fabsf(gx), ay = fabsf(gy);
    int b;
    if (ay <= 0.4142135623730951f * ax) b = 0;
    else if (ay >= 2.414213562373095f * ax) b = 2;
    else b = ((gx > 0.f) == (gy > 0.f)) ? 1 : 3;

    const int pdy[4] = {0, 1, 1, 1};
    const int pdx[4] = {1, 1, 0, -1};
    float n1 = sm[ty + 1 + pdy[b]][tx + 1 + pdx[b]];
    float n2 = sm[ty + 1 - pdy[b]][tx + 1 - pdx[b]];
    float nms = (mag >= n1 && mag >= n2) ? mag : 0.f;

    u64 strong = __ballot(nms >= 0.2f);
    u64 weak   = __ballot(nms >= 0.1f);   // inclusive of strong: harmless
    if (tx == 0) {
        size_t off = ((size_t)n * H + (y0 + ty)) * 8 + blockIdx.x;
        strongP[off] = strong;
        weakP[off] = weak;
    }
}

// ---------------------------------------------------------------------------
// Kernel 2: bit-parallel hysteresis (10 iters, exact via light cone) + diff
// count. One wave per 32x32 tile per image-pair; lane l holds row y0-10+l
// (52 active lanes) as a 64-bit window covering x0-10 .. x0+53.
// ---------------------------------------------------------------------------
__device__ __forceinline__ u64 ldw(const u64* p, int img, int y, int w, bool ok) {
    return (ok && w >= 0 && w < 8) ? p[((size_t)img * H + y) * 8 + w] : 0ULL;
}

__global__ __launch_bounds__(256) void k_hyst(const u64* __restrict__ strongP,
                                              const u64* __restrict__ weakP,
                                              unsigned int* __restrict__ cnt) {
    const int wave = blockIdx.x * 4 + (threadIdx.x >> 6);
    const int lane = threadIdx.x & 63;
    const int tile = wave & 255;
    const int pair = wave >> 8;          // 0..15
    const int tx0 = (tile & 15) * 32;
    const int ty0 = (tile >> 4) * 32;

    const int y = ty0 - 10 + lane;
    const bool rowok = (lane < 52) && (y >= 0) && (y < H);
    const int s = tx0 - 10;
    const int w0i = s >> 6;              // arithmetic shift: -10>>6 = -1
    const int r = s & 63;                // in {22,54}, never 0

    const int imgA = pair, imgB = pair + 16;
    u64 sA, wA, sB, wB;
    {
        u64 lo, hi;
        lo = ldw(strongP, imgA, y, w0i, rowok); hi = ldw(strongP, imgA, y, w0i + 1, rowok);
        sA = (lo >> r) | (hi << (64 - r));
        lo = ldw(weakP, imgA, y, w0i, rowok);   hi = ldw(weakP, imgA, y, w0i + 1, rowok);
        wA = (lo >> r) | (hi << (64 - r));
        lo = ldw(strongP, imgB, y, w0i, rowok); hi = ldw(strongP, imgB, y, w0i + 1, rowok);
        sB = (lo >> r) | (hi << (64 - r));
        lo = ldw(weakP, imgB, y, w0i, rowok);   hi = ldw(weakP, imgB, y, w0i + 1, rowok);
        wB = (lo >> r) | (hi << (64 - r));
    }

#pragma unroll
    for (int it = 0; it < 10; it++) {
        u64 up = __shfl_up(sA, 1), dn = __shfl_down(sA, 1);
        u64 t = up | sA | dn;
        sA |= (t | (t << 1) | (t >> 1)) & wA;
        up = __shfl_up(sB, 1); dn = __shfl_down(sB, 1);
        t = up | sB | dn;
        sB |= (t | (t << 1) | (t >> 1)) & wB;
    }

    // central 32x32: lanes 10..41, bits 10..41
    unsigned int c = 0;
    if (lane >= 10 && lane < 42) {
        const u64 mask = ((1ULL << 42) - (1ULL << 10));
        c = (unsigned int)__popcll((sA ^ sB) & mask);
    }
#pragma unroll
    for (int off = 32; off > 0; off >>= 1) c += __shfl_down(c, off);
    if (lane == 0) atomicAdd(cnt, c);
}

__global__ void k_final(const unsigned int* __restrict__ cnt,
                        float* __restrict__ out) {
    out[0] = (float)cnt[0] * (1.0f / 4194304.0f);   // / (16*512*512)
}

extern "C" void kernel_launch(void* const* d_in, const int* in_sizes, int n_in,
                              void* d_out, int out_size, void* d_ws, size_t ws_size,
                              hipStream_t stream) {
    const float* yhat = (const float*)d_in[0];
    const float* yy = (const float*)d_in[1];

    u64* strongP = (u64*)d_ws;                   // 32*512*8 u64 = 1 MB
    u64* weakP = strongP + (size_t)NIMG * H * 8; // 1 MB
    unsigned int* cnt = (unsigned int*)(weakP + (size_t)NIMG * H * 8);

    hipMemsetAsync(cnt, 0, sizeof(unsigned int), stream);

    dim3 eblk(EBX, EBY);
    dim3 egrd(W / EBX, H / EBY, NIMG);
    k_edges<<<egrd, eblk, 0, stream>>>(yhat, yy, strongP, weakP);

    // 256 tiles x 16 pairs = 4096 waves, 4 waves/block
    k_hyst<<<1024, 256, 0, stream>>>(strongP, weakP, cnt);
    k_final<<<1, 1, 0, stream>>>(cnt, (float*)d_out);
}

// Round 3
// 153.238 us; speedup vs baseline: 2.7552x; 1.3913x over previous
//
#include <hip/hip_runtime.h>
#include <math.h>

#define H 512
#define W 512
#define IMG (H*W)
#define NIMG 32           // 16 images from y_hat + 16 from y

typedef unsigned long long u64;

__device__ __forceinline__ int reflect_idx(int i, int n) {
    // jnp.pad mode="reflect": -1 -> 1, -2 -> 2, n -> n-2, n+1 -> n-3
    if (i < 0) i = -i;
    if (i >= n) i = 2 * n - 2 - i;
    return i;
}

// ---------------------------------------------------------------------------
// Kernel 1: gray + separable 5x5 Gaussian (reflect) + Sobel (reflect) + mag +
// direction bin + NMS (zero-pad neighbors) + double threshold, emitted as
// strong/weak BITPLANES via __ballot. Tile 64x16, block (64,8)=512 threads,
// 2 output rows per thread. Plane layout: plane[img][row][word], 8 u64/row.
// ---------------------------------------------------------------------------
#define EBX 64
#define EBY 16

__global__ __launch_bounds__(512) void k_edges(const float* __restrict__ yhat,
                                               const float* __restrict__ yy,
                                               u64* __restrict__ strongP,
                                               u64* __restrict__ weakP) {
    __shared__ float sg[EBY + 8][EBX + 8 + 1];   // gray,  24 x 72 (+pad)
    __shared__ float ht[EBY + 8][EBX + 4 + 1];   // h-blur,24 x 68 (+pad)
    __shared__ float sb[EBY + 4][EBX + 4 + 1];   // blur,  20 x 68 (+pad)
    __shared__ float sm[EBY + 2][EBX + 2 + 1];   // mag,   18 x 66 (+pad)

    const int n = blockIdx.z;
    const float* src = (n < 16) ? (yhat + (size_t)n * 3 * IMG)
                                : (yy + (size_t)(n - 16) * 3 * IMG);
    const int x0 = blockIdx.x * EBX;
    const int y0 = blockIdx.y * EBY;
    const int tid = threadIdx.y * EBX + threadIdx.x;

    const float w0 = 0.05448868454964294f, w1 = 0.24420134200323332f,
                w2 = 0.4026199468942475f;
    const float wk[5] = {w0, w1, w2, w1, w0};

    // ---- gray tile, halo 4, reflect: 24 x 72 ----
    for (int idx = tid; idx < 24 * 72; idx += 512) {
        int sy = idx / 72, sx = idx % 72;
        int iy = reflect_idx(y0 - 4 + sy, H);
        int ix = reflect_idx(x0 - 4 + sx, W);
        float r = src[(size_t)iy * W + ix];
        float g = src[(size_t)IMG + (size_t)iy * W + ix];
        float b = src[(size_t)2 * IMG + (size_t)iy * W + ix];
        sg[sy][sx] = 0.299f * r + 0.587f * g + 0.114f * b;
    }
    __syncthreads();

    // ---- horizontal blur: 24 x 68, col center = x0-2+sx ----
    for (int idx = tid; idx < 24 * 68; idx += 512) {
        int sy = idx / 68, sx = idx % 68;
        float a = 0.f;
#pragma unroll
        for (int v = 0; v < 5; v++) a += wk[v] * sg[sy][sx + v];
        ht[sy][sx] = a;
    }
    __syncthreads();

    // ---- vertical blur: 20 x 68, row center = y0-2+sy ----
    for (int idx = tid; idx < 20 * 68; idx += 512) {
        int sy = idx / 68, sx = idx % 68;
        float a = 0.f;
#pragma unroll
        for (int u = 0; u < 5; u++) a += wk[u] * ht[sy + u][sx];
        sb[sy][sx] = a;
    }
    __syncthreads();

    // ---- magnitude: 18 x 66 at (y0-1+my, x0-1+mx); zero outside image ----
    for (int idx = tid; idx < 18 * 66; idx += 512) {
        int my = idx / 66, mx = idx % 66;
        int iy = y0 - 1 + my, ix = x0 - 1 + mx;
        float m = 0.f;
        if (iy >= 0 && iy < H && ix >= 0 && ix < W) {
            float a00 = sb[my][mx],     a01 = sb[my][mx + 1],     a02 = sb[my][mx + 2];
            float a10 = sb[my + 1][mx],                           a12 = sb[my + 1][mx + 2];
            float a20 = sb[my + 2][mx], a21 = sb[my + 2][mx + 1], a22 = sb[my + 2][mx + 2];
            float gx = (a02 + 2.f * a12 + a22) - (a00 + 2.f * a10 + a20);
            float gy = (a20 + 2.f * a21 + a22) - (a00 + 2.f * a01 + a02);
            m = sqrtf(gx * gx + gy * gy + 1e-12f);
        }
        sm[my][mx] = m;
    }
    __syncthreads();

    // ---- NMS + double threshold: 2 rows per thread ----
    const int tx = threadIdx.x;
#pragma unroll
    for (int half = 0; half < 2; half++) {
        const int ry = threadIdx.y + half * 8;   // output row within tile, 0..15
        float a00 = sb[ry + 1][tx + 1], a01 = sb[ry + 1][tx + 2], a02 = sb[ry + 1][tx + 3];
        float a10 = sb[ry + 2][tx + 1],                           a12 = sb[ry + 2][tx + 3];
        float a20 = sb[ry + 3][tx + 1], a21 = sb[ry + 3][tx + 2], a22 = sb[ry + 3][tx + 3];
        float gx = (a02 + 2.f * a12 + a22) - (a00 + 2.f * a10 + a20);
        float gy = (a20 + 2.f * a21 + a22) - (a00 + 2.f * a01 + a02);
        float mag = sm[ry + 1][tx + 1];

        // bin = mod(round(atan2(gy,gx)/(pi/4)),4) via slope comparison
        float ax = fabsf(gx), ay = fabsf(gy);
        int dy, dx;
        if (ay <= 0.4142135623730951f * ax) { dy = 0; dx = 1; }
        else if (ay >= 2.414213562373095f * ax) { dy = 1; dx = 0; }
        else { dy = 1; dx = ((gx > 0.f) == (gy > 0.f)) ? 1 : -1; }

        float n1 = sm[ry + 1 + dy][tx + 1 + dx];
        float n2 = sm[ry + 1 - dy][tx + 1 - dx];
        float nms = (mag >= n1 && mag >= n2) ? mag : 0.f;

        u64 strong = __ballot(nms >= 0.2f);
        u64 weak   = __ballot(nms >= 0.1f);   // superset of strong: harmless
        if (tx == 0) {
            size_t off = ((size_t)n * H + (y0 + ry)) * 8 + blockIdx.x;
            strongP[off] = strong;
            weakP[off] = weak;
        }
    }
}

// ---------------------------------------------------------------------------
// Kernel 2: bit-parallel hysteresis (10 iters, exact via light cone) + diff
// count. One wave per 32x32 tile per image-pair; lane l holds row ty0-10+l
// (52 active lanes) as a 64-bit window covering x0-10 .. x0+53.
// Per-block partial sums (NO global atomics).
// ---------------------------------------------------------------------------
__device__ __forceinline__ u64 ldw(const u64* p, int img, int y, int w, bool ok) {
    return (ok && w >= 0 && w < 8) ? p[((size_t)img * H + y) * 8 + w] : 0ULL;
}

__global__ __launch_bounds__(256) void k_hyst(const u64* __restrict__ strongP,
                                              const u64* __restrict__ weakP,
                                              unsigned int* __restrict__ partials) {
    __shared__ unsigned int part[4];
    const int wy = threadIdx.x >> 6;
    const int wave = blockIdx.x * 4 + wy;
    const int lane = threadIdx.x & 63;
    const int tile = wave & 255;
    const int pair = wave >> 8;          // 0..15
    const int tx0 = (tile & 15) * 32;
    const int ty0 = (tile >> 4) * 32;

    const int y = ty0 - 10 + lane;
    const bool rowok = (lane < 52) && (y >= 0) && (y < H);
    const int s = tx0 - 10;
    const int w0i = s >> 6;              // arithmetic shift: -10>>6 = -1
    const int r = s & 63;                // in {22,54}, never 0

    const int imgA = pair, imgB = pair + 16;
    u64 sA, wA, sB, wB;
    {
        u64 lo, hi;
        lo = ldw(strongP, imgA, y, w0i, rowok); hi = ldw(strongP, imgA, y, w0i + 1, rowok);
        sA = (lo >> r) | (hi << (64 - r));
        lo = ldw(weakP, imgA, y, w0i, rowok);   hi = ldw(weakP, imgA, y, w0i + 1, rowok);
        wA = (lo >> r) | (hi << (64 - r));
        lo = ldw(strongP, imgB, y, w0i, rowok); hi = ldw(strongP, imgB, y, w0i + 1, rowok);
        sB = (lo >> r) | (hi << (64 - r));
        lo = ldw(weakP, imgB, y, w0i, rowok);   hi = ldw(weakP, imgB, y, w0i + 1, rowok);
        wB = (lo >> r) | (hi << (64 - r));
    }

#pragma unroll
    for (int it = 0; it < 10; it++) {
        u64 up = __shfl_up(sA, 1), dn = __shfl_down(sA, 1);
        u64 t = up | sA | dn;
        sA |= (t | (t << 1) | (t >> 1)) & wA;
        up = __shfl_up(sB, 1); dn = __shfl_down(sB, 1);
        t = up | sB | dn;
        sB |= (t | (t << 1) | (t >> 1)) & wB;
    }

    // central 32x32: lanes 10..41, bits 10..41
    unsigned int c = 0;
    if (lane >= 10 && lane < 42) {
        const u64 mask = ((1ULL << 42) - (1ULL << 10));
        c = (unsigned int)__popcll((sA ^ sB) & mask);
    }
#pragma unroll
    for (int off = 32; off > 0; off >>= 1) c += __shfl_down(c, off);
    if (lane == 0) part[wy] = c;
    __syncthreads();
    if (threadIdx.x == 0)
        partials[blockIdx.x] = part[0] + part[1] + part[2] + part[3];
}

// ---------------------------------------------------------------------------
// Kernel 3: sum 1024 partials, scale, write scalar. One block.
// ---------------------------------------------------------------------------
__global__ __launch_bounds__(256) void k_final(const unsigned int* __restrict__ partials,
                                               float* __restrict__ out) {
    __shared__ unsigned int part[4];
    unsigned int c = 0;
    for (int i = threadIdx.x; i < 1024; i += 256) c += partials[i];
#pragma unroll
    for (int off = 32; off > 0; off >>= 1) c += __shfl_down(c, off);
    const int lane = threadIdx.x & 63;
    const int wy = threadIdx.x >> 6;
    if (lane == 0) part[wy] = c;
    __syncthreads();
    if (threadIdx.x == 0)
        out[0] = (float)(part[0] + part[1] + part[2] + part[3]) * (1.0f / 4194304.0f);
}

extern "C" void kernel_launch(void* const* d_in, const int* in_sizes, int n_in,
                              void* d_out, int out_size, void* d_ws, size_t ws_size,
                              hipStream_t stream) {
    const float* yhat = (const float*)d_in[0];
    const float* yy = (const float*)d_in[1];

    u64* strongP = (u64*)d_ws;                   // 32*512*8 u64 = 1 MB
    u64* weakP = strongP + (size_t)NIMG * H * 8; // 1 MB
    unsigned int* partials = (unsigned int*)(weakP + (size_t)NIMG * H * 8); // 4 KB

    dim3 eblk(EBX, 8);
    dim3 egrd(W / EBX, H / EBY, NIMG);
    k_edges<<<egrd, eblk, 0, stream>>>(yhat, yy, strongP, weakP);

    // 256 tiles x 16 pairs = 4096 waves, 4 waves/block
    k_hyst<<<1024, 256, 0, stream>>>(strongP, weakP, partials);
    k_final<<<1, 256, 0, stream>>>(partials, (float*)d_out);
}